// Round 21
// baseline (394.171 us; speedup 1.0000x reference)
//
#include <hip/hip_runtime.h>
#include <hip/hip_bf16.h>

#define GXGY 172800   // 480*360
#define GYC  360
#define NKEYS 345600  // 2*GXGY  (B=2)
#define SCAN_NB 338   // ceil(345600/1024)
#define STATS_NBLK 256
#define SQOFF 65536   // partials sumsq offset (floats)

typedef short short8_t __attribute__((ext_vector_type(8)));
typedef float floatx4 __attribute__((ext_vector_type(4)));

// ---------------- bf16 helpers ----------------
__device__ inline float bf2f(unsigned short u) {
  union { unsigned int i; float f; } v;
  v.i = ((unsigned int)u) << 16;
  return v.f;
}
__device__ inline unsigned short f2bf(float f) {
  union { float f; unsigned int i; } v;
  v.f = f;
  unsigned int lsb = (v.i >> 16) & 1u;
  return (unsigned short)((v.i + 0x7FFFu + lsb) >> 16);  // RNE (cold paths)
}
// HW packed RNE conversion: 2 f32 -> packed bf16x2 (v_cvt_pk_bf16_f32), lo = a
__device__ inline unsigned int pk2bf(float lo, float hi) {
  __hip_bfloat162 h = __float22bfloat162_rn(float2{lo, hi});
  union { __hip_bfloat162 h; unsigned int u; } c;
  c.h = h;
  return c.u;
}
// affine+relu two packed bf16 -> packed bf16 (hot path, HW cvt_pk)
__device__ inline unsigned int aff2(unsigned int pr, float a0, float c0, float a1, float c1) {
  union { unsigned int i; float f; } t0, t1;
  t0.i = pr << 16; t1.i = pr & 0xFFFF0000u;
  float v0 = fmaxf(fmaf(t0.f, a0, c0), 0.f);
  float v1 = fmaxf(fmaf(t1.f, a1, c1), 0.f);
  return pk2bf(v0, v1);
}

// ---------------- xy dtype probe: int32 pairs vs int64 ----------------
__global__ __launch_bounds__(1024) void k_detect(const int* __restrict__ xy, int* __restrict__ flag) {
  __shared__ int any;
  if (threadIdx.x == 0) any = 0;
  __syncthreads();
  if (xy[threadIdx.x * 2 + 1] != 0) atomicOr(&any, 1);
  __syncthreads();
  if (threadIdx.x == 0) *flag = any;  // 1 -> int32, 0 -> int64
}

__device__ inline void load_xy(const int* xy, const int* flag, int p, int& ix, int& iy) {
  if (*flag) { ix = xy[(size_t)p * 2]; iy = xy[(size_t)p * 2 + 1]; }
  else       { ix = xy[(size_t)p * 4]; iy = xy[(size_t)p * 4 + 2]; }
}

// ---------------- unique via dense histogram + scans ----------------

__global__ __launch_bounds__(256) void k_count(const int* __restrict__ xy, const int* __restrict__ flag,
                                               int* __restrict__ counts, int P, int N) {
  int p = blockIdx.x * 256 + threadIdx.x;
  if (p >= P) return;
  int ix, iy;
  load_xy(xy, flag, p, ix, iy);
  int key = ((p >= N) ? GXGY : 0) + ix * GYC + iy;
  atomicAdd(&counts[key], 1);
}

// fused dual scan: occupancy flags -> prefix, counts -> prefixS (one counts read)
__global__ __launch_bounds__(256) void k_scan1b(const int* __restrict__ counts,
                                                int* __restrict__ prefix, int* __restrict__ prefixS,
                                                int* __restrict__ blockTot, int* __restrict__ blockTotS) {
  __shared__ int sf[256], sv[256];
  int base = blockIdx.x * 1024;
  int f[4], c[4];
  int tf = 0, tv = 0;
#pragma unroll
  for (int i = 0; i < 4; ++i) {
    int k = base + threadIdx.x * 4 + i;
    int cnt = (k < NKEYS) ? counts[k] : 0;
    c[i] = cnt;
    f[i] = (cnt > 0) ? 1 : 0;
    tf += f[i];
    tv += c[i];
  }
  sf[threadIdx.x] = tf;
  sv[threadIdx.x] = tv;
  __syncthreads();
  for (int off = 1; off < 256; off <<= 1) {
    int a = (threadIdx.x >= off) ? sf[threadIdx.x - off] : 0;
    int b = (threadIdx.x >= off) ? sv[threadIdx.x - off] : 0;
    __syncthreads();
    if (threadIdx.x >= off) {
      sf[threadIdx.x] += a;
      sv[threadIdx.x] += b;
    }
    __syncthreads();
  }
  int runF = (threadIdx.x == 0) ? 0 : sf[threadIdx.x - 1];
  int runV = (threadIdx.x == 0) ? 0 : sv[threadIdx.x - 1];
#pragma unroll
  for (int i = 0; i < 4; ++i) {
    int k = base + threadIdx.x * 4 + i;
    if (k < NKEYS) {
      prefix[k] = runF;
      prefixS[k] = runV;
    }
    runF += f[i];
    runV += c[i];
  }
  if (threadIdx.x == 255) {
    blockTot[blockIdx.x] = sf[255];
    blockTotS[blockIdx.x] = sv[255];
  }
}

// fused pair of block-level scans: block 0 -> blockOff(+dU), block 1 -> blockOffS
__global__ __launch_bounds__(512) void k_scan2b(const int* __restrict__ blockTot,
                                                const int* __restrict__ blockTotS,
                                                int* __restrict__ blockOff, int* __restrict__ blockOffS,
                                                int* __restrict__ dU) {
  __shared__ int s[512];
  const int* in = (blockIdx.x == 0) ? blockTot : blockTotS;
  int* out = (blockIdx.x == 0) ? blockOff : blockOffS;
  int v = (threadIdx.x < SCAN_NB) ? in[threadIdx.x] : 0;
  s[threadIdx.x] = v;
  __syncthreads();
  for (int off = 1; off < 512; off <<= 1) {
    int t = (threadIdx.x >= off) ? s[threadIdx.x - off] : 0;
    __syncthreads();
    if (threadIdx.x >= off) s[threadIdx.x] += t;
    __syncthreads();
  }
  if (threadIdx.x < SCAN_NB) out[threadIdx.x] = s[threadIdx.x] - v;  // exclusive
  if (blockIdx.x == 0 && threadIdx.x == 511) *dU = s[511];
}

// fused fillunq + pad + cursor-reset + rankCS pad-zero (grid covers P >= NKEYS)
__global__ __launch_bounds__(256) void k_fillpad(int* __restrict__ counts, const int* __restrict__ prefix,
                                                 const int* __restrict__ blockOff,
                                                 const int* __restrict__ prefixS, const int* __restrict__ blockOffS,
                                                 const int* __restrict__ dU,
                                                 float* __restrict__ out_unq, int2* __restrict__ rankCS, int P) {
  int i = blockIdx.x * 256 + threadIdx.x;
  if (i < NKEYS) {
    int cnt = counts[i];
    if (cnt > 0) {
      counts[i] = 0;  // cursor reset for k_sortpts
      int r = prefix[i] + blockOff[i >> 10];
      rankCS[r] = make_int2(cnt, prefixS[i] + blockOffS[i >> 10]);
      int b = i / GXGY;
      int rem = i % GXGY;
      out_unq[(size_t)r * 3 + 0] = (float)b;
      out_unq[(size_t)r * 3 + 1] = (float)(rem / GYC);
      out_unq[(size_t)r * 3 + 2] = (float)(rem % GYC);
    }
  }
  if (i < P && i >= *dU) {  // pad ranks: key=-1 -> (-1, 479, 359); zero (cnt,start)
    out_unq[(size_t)i * 3 + 0] = -1.f;
    out_unq[(size_t)i * 3 + 1] = 479.f;
    out_unq[(size_t)i * 3 + 2] = 359.f;
    rankCS[i] = make_int2(0, 0);
  }
}

// counting sort: slot = keyStart + cursor (counts reused as cursor, reset by k_fillpad)
__global__ __launch_bounds__(256) void k_sortpts(const int* __restrict__ xy, const int* __restrict__ flag,
                                                 const int* __restrict__ prefixS,
                                                 const int* __restrict__ blockOffS, int* __restrict__ cursor,
                                                 int* __restrict__ sorted, int P, int N) {
  int p = blockIdx.x * 256 + threadIdx.x;
  if (p >= P) return;
  int ix, iy;
  load_xy(xy, flag, p, ix, iy);
  int key = ((p >= N) ? GXGY : 0) + ix * GYC + iy;
  int slot = prefixS[key] + blockOffS[key >> 10] + atomicAdd(&cursor[key], 1);
  sorted[slot] = p;
}

// ---------------- BN0 stats + finalize ----------------

__global__ __launch_bounds__(256) void k_stats9(const float* __restrict__ x, int P, float* __restrict__ partials) {
  float s[9] = {0}, q[9] = {0};
  for (int p = blockIdx.x * 256 + threadIdx.x; p < P; p += STATS_NBLK * 256) {
#pragma unroll
    for (int k = 0; k < 9; ++k) {
      float v = x[(size_t)p * 9 + k];
      s[k] += v;
      q[k] += v * v;
    }
  }
  __shared__ float ls[256 * 9];
#pragma unroll
  for (int k = 0; k < 9; ++k) ls[threadIdx.x * 9 + k] = s[k];
  __syncthreads();
  if (threadIdx.x < 9) {
    float acc = 0;
    for (int t = 0; t < 256; ++t) acc += ls[t * 9 + threadIdx.x];
    partials[blockIdx.x * 9 + threadIdx.x] = acc;
  }
  __syncthreads();
#pragma unroll
  for (int k = 0; k < 9; ++k) ls[threadIdx.x * 9 + k] = q[k];
  __syncthreads();
  if (threadIdx.x < 9) {
    float acc = 0;
    for (int t = 0; t < 256; ++t) acc += ls[t * 9 + threadIdx.x];
    partials[SQOFF + blockIdx.x * 9 + threadIdx.x] = acc;
  }
}

__global__ void k_finalize(const float* __restrict__ partials, const float* __restrict__ gam,
                           const float* __restrict__ bet, float* __restrict__ ac, int F, int P) {
  int f = threadIdx.x;
  if (f >= F) return;
  float s = 0.f, q = 0.f;
  for (int blk = 0; blk < STATS_NBLK; ++blk) {
    s += partials[blk * F + f];
    q += partials[SQOFF + blk * F + f];
  }
  float mean = s / (float)P;
  float var = q / (float)P - mean * mean;
  float A = gam[f] * rsqrtf(var + 1e-5f);
  ac[f] = A;
  ac[256 + f] = bet[f] - mean * A;
}

__global__ void k_finalize_at(const float* __restrict__ stats, const float* __restrict__ gam,
                              const float* __restrict__ bet, float* __restrict__ ac, int F, int P) {
  int f = threadIdx.x;
  if (f >= F) return;
  float mean = stats[f] / (float)P;
  float var = stats[256 + f] / (float)P - mean * mean;
  float A = gam[f] * rsqrtf(var + 1e-5f);
  ac[f] = A;
  ac[256 + f] = bet[f] - mean * A;
}

// ---------------- stage 1 (K=9): tiled/vectorized + fused BN1 stats ----------------
__global__ __launch_bounds__(256) void k_stage1s(const float* __restrict__ x, const float* __restrict__ ac,
                                                 const float* __restrict__ W1, const float* __restrict__ b1,
                                                 unsigned short* __restrict__ y1, float* __restrict__ stats,
                                                 int P) {
  __shared__ float sW[576];
  __shared__ float sb[64];
  __shared__ float sa[9], sc[9];
  __shared__ float xT[288];
  __shared__ float gS[256], gQ[256];
  const int tid = threadIdx.x;
  for (int i = tid; i < 576; i += 256) sW[i] = W1[i];
  if (tid < 64) sb[tid] = b1[tid];
  if (tid < 9) {
    sa[tid] = ac[tid];
    sc[tid] = ac[256 + tid];
  }
  const int row_l = tid >> 3;   // 0..31
  const int cg = tid & 7;       // col group (8 cols)
  const int tiles = P >> 5;     // P % 32 == 0
  float sS[8] = {}, sQ[8] = {};
  float pre0 = 0.f, pre1 = 0.f;
  int tile = blockIdx.x;
  if (tile < tiles) {
    size_t base = (size_t)tile * 288;
    pre0 = x[base + tid];
    if (tid < 32) pre1 = x[base + 256 + tid];
  }
  __syncthreads();
  for (; tile < tiles; tile += gridDim.x) {
    xT[tid] = pre0;
    if (tid < 32) xT[256 + tid] = pre1;
    __syncthreads();
    int nt = tile + gridDim.x;
    if (nt < tiles) {
      size_t base = (size_t)nt * 288;
      pre0 = x[base + tid];
      if (tid < 32) pre1 = x[base + 256 + tid];
    }
    float acc[8];
#pragma unroll
    for (int c = 0; c < 8; ++c) acc[c] = sb[cg * 8 + c];
#pragma unroll
    for (int k = 0; k < 9; ++k) {
      float xn = fmaf(xT[row_l * 9 + k], sa[k], sc[k]);
#pragma unroll
      for (int c = 0; c < 8; ++c) acc[c] = fmaf(xn, sW[k * 64 + cg * 8 + c], acc[c]);
    }
    uint4 o;
    o.x = pk2bf(acc[0], acc[1]);
    o.y = pk2bf(acc[2], acc[3]);
    o.z = pk2bf(acc[4], acc[5]);
    o.w = pk2bf(acc[6], acc[7]);
    *(uint4*)&y1[((size_t)tile * 32 + row_l) * 64 + cg * 8] = o;
#pragma unroll
    for (int c = 0; c < 8; ++c) {
      sS[c] += acc[c];
      sQ[c] += acc[c] * acc[c];
    }
    __syncthreads();  // xT consumed before next overwrite
  }
#pragma unroll
  for (int c = 0; c < 8; ++c) {
    sS[c] += __shfl_xor(sS[c], 8);
    sS[c] += __shfl_xor(sS[c], 16);
    sS[c] += __shfl_xor(sS[c], 32);
    sQ[c] += __shfl_xor(sQ[c], 8);
    sQ[c] += __shfl_xor(sQ[c], 16);
    sQ[c] += __shfl_xor(sQ[c], 32);
  }
  int lane = tid & 63, wv = tid >> 6;
  if (lane < 8) {
#pragma unroll
    for (int c = 0; c < 8; ++c) {
      gS[wv * 64 + lane * 8 + c] = sS[c];
      gQ[wv * 64 + lane * 8 + c] = sQ[c];
    }
  }
  __syncthreads();
  if (tid < 64) {
    float S = gS[tid] + gS[64 + tid] + gS[128 + tid] + gS[192 + tid];
    float Q = gQ[tid] + gQ[64 + tid] + gQ[128 + tid] + gQ[192 + tid];
    atomicAdd(&stats[tid], S);
    atomicAdd(&stats[256 + tid], Q);
  }
}

// ---------------- MFMA GEMM stage 2 (K=64, N=128) ----------------
template <int K>
__global__ __launch_bounds__(256, 4) void k_gemmM(const unsigned short* __restrict__ X,
                                                  const float* __restrict__ acIn,
                                                  const float* __restrict__ W, const float* __restrict__ bias,
                                                  unsigned short* __restrict__ Y, float* __restrict__ stats,
                                                  int N, int P) {
  constexpr int SEGS = K / 8;
  constexpr int NIT = K / 32;          // uint4 staging regs per thread
  constexpr int KPA = K + 8;           // A / W^T row stride (u16)
  constexpr int OFF_C = 64 * KPA * 2;  // Csm after A
  constexpr int OFF_AC = OFF_C + 64 * 136 * 2;
  constexpr int OFF_B = OFF_AC + 512 * 4;
  constexpr int SMEM = OFF_B + 128 * 4;
  static_assert(64 * KPA * 2 + 64 * 136 * 2 >= 128 * KPA * 2, "WTtmp alias fits in A+Csm");
  __shared__ __align__(16) char smem[SMEM];
  unsigned short* A   = (unsigned short*)smem;             // [64][KPA]
  unsigned short* Csm = (unsigned short*)(smem + OFF_C);   // [64][136]
  unsigned short* WTt = (unsigned short*)smem;             // transient [128][KPA], aliases A+Csm
  float* acL = (float*)(smem + OFF_AC);
  float* bL  = (float*)(smem + OFF_B);

  const int tid = threadIdx.x;
  const int nq = blockIdx.y;

  for (int i = tid; i < 128 * K; i += 256) {
    int k = i >> 7, n = i & 127;
    WTt[n * KPA + k] = f2bf(W[(size_t)k * N + nq * 128 + n]);
  }
  for (int i = tid; i < 512; i += 256) acL[i] = acIn[i];
  if (tid < 128) bL[tid] = bias[nq * 128 + tid];
  __syncthreads();

  const int lane = tid & 63;
  const int w = tid >> 6;
  const int li = lane & 15, lg = lane >> 4;
  const int cb = 32 * w;

  short8_t bfr[2][K / 32];
#pragma unroll
  for (int t = 0; t < 2; ++t)
#pragma unroll
    for (int s = 0; s < K / 32; ++s)
      bfr[t][s] = *(const short8_t*)&WTt[(cb + 16 * t + li) * KPA + 32 * s + 8 * lg];
  __syncthreads();  // WTt dead; A/Csm live from here

  const int tiles = P >> 6;
  float sS[2] = {0.f, 0.f}, sQ[2] = {0.f, 0.f};
  uint4 pre[NIT];
  int tile = blockIdx.x;
  if (tile < tiles) {
#pragma unroll
    for (int it = 0; it < NIT; ++it) {
      int i = tid + it * 256;
      int row = i / SEGS, seg = i % SEGS;
      pre[it] = *(const uint4*)&X[((size_t)tile * 64 + row) * K + seg * 8];
    }
  }
  for (; tile < tiles; tile += gridDim.x) {
    const size_t row0 = (size_t)tile * 64;
#pragma unroll
    for (int it = 0; it < NIT; ++it) {
      int i = tid + it * 256;
      int row = i / SEGS, seg = i % SEGS;
      const float* ap = &acL[seg * 8];
      const float* cp = &acL[256 + seg * 8];
      uint4 o;
      o.x = aff2(pre[it].x, ap[0], cp[0], ap[1], cp[1]);
      o.y = aff2(pre[it].y, ap[2], cp[2], ap[3], cp[3]);
      o.z = aff2(pre[it].z, ap[4], cp[4], ap[5], cp[5]);
      o.w = aff2(pre[it].w, ap[6], cp[6], ap[7], cp[7]);
      *(uint4*)&A[row * KPA + seg * 8] = o;
    }
    __syncthreads();  // B1
    int nt = tile + gridDim.x;
    if (nt < tiles) {
#pragma unroll
      for (int it = 0; it < NIT; ++it) {
        int i = tid + it * 256;
        int row = i / SEGS, seg = i % SEGS;
        pre[it] = *(const uint4*)&X[((size_t)nt * 64 + row) * K + seg * 8];
      }
    }

    floatx4 acc[4][2];
#pragma unroll
    for (int m = 0; m < 4; ++m)
#pragma unroll
      for (int t = 0; t < 2; ++t) acc[m][t] = (floatx4){0.f, 0.f, 0.f, 0.f};

#pragma unroll
    for (int s = 0; s < K / 32; ++s) {
      const int ko = 32 * s + 8 * lg;
      short8_t af0 = *(const short8_t*)&A[(li) * KPA + ko];
      short8_t af1 = *(const short8_t*)&A[(16 + li) * KPA + ko];
      short8_t af2 = *(const short8_t*)&A[(32 + li) * KPA + ko];
      short8_t af3 = *(const short8_t*)&A[(48 + li) * KPA + ko];
      acc[0][0] = __builtin_amdgcn_mfma_f32_16x16x32_bf16(af0, bfr[0][s], acc[0][0], 0, 0, 0);
      acc[1][0] = __builtin_amdgcn_mfma_f32_16x16x32_bf16(af1, bfr[0][s], acc[1][0], 0, 0, 0);
      acc[2][0] = __builtin_amdgcn_mfma_f32_16x16x32_bf16(af2, bfr[0][s], acc[2][0], 0, 0, 0);
      acc[3][0] = __builtin_amdgcn_mfma_f32_16x16x32_bf16(af3, bfr[0][s], acc[3][0], 0, 0, 0);
      acc[0][1] = __builtin_amdgcn_mfma_f32_16x16x32_bf16(af0, bfr[1][s], acc[0][1], 0, 0, 0);
      acc[1][1] = __builtin_amdgcn_mfma_f32_16x16x32_bf16(af1, bfr[1][s], acc[1][1], 0, 0, 0);
      acc[2][1] = __builtin_amdgcn_mfma_f32_16x16x32_bf16(af2, bfr[1][s], acc[2][1], 0, 0, 0);
      acc[3][1] = __builtin_amdgcn_mfma_f32_16x16x32_bf16(af3, bfr[1][s], acc[3][1], 0, 0, 0);
    }

#pragma unroll
    for (int m = 0; m < 4; ++m)
#pragma unroll
      for (int t = 0; t < 2; ++t) {
        int col = cb + 16 * t + li;
        float bb = bL[col];
#pragma unroll
        for (int rp = 0; rp < 2; ++rp) {
          int rowc = 16 * m + 4 * lg + 2 * rp;
          float v0 = acc[m][t][2 * rp] + bb;
          float v1 = acc[m][t][2 * rp + 1] + bb;
          unsigned int u = pk2bf(v0, v1);
          Csm[rowc * 136 + col] = (unsigned short)(u & 0xFFFFu);
          Csm[(rowc + 1) * 136 + col] = (unsigned short)(u >> 16);
          sS[t] += v0 + v1;
          sQ[t] += v0 * v0 + v1 * v1;
        }
      }
    __syncthreads();  // B2
    for (int i = tid; i < 1024; i += 256) {
      int rowc = i >> 4, seg = i & 15;
      *(uint4*)&Y[(row0 + rowc) * N + nq * 128 + seg * 8] = *(const uint4*)&Csm[rowc * 136 + seg * 8];
    }
  }

#pragma unroll
  for (int t = 0; t < 2; ++t) {
    float s = sS[t];
    s += __shfl_xor(s, 16);
    s += __shfl_xor(s, 32);
    float q = sQ[t];
    q += __shfl_xor(q, 16);
    q += __shfl_xor(q, 32);
    if (lane < 16) {
      int col = nq * 128 + cb + 16 * t + li;
      atomicAdd(&stats[col], s);
      atomicAdd(&stats[256 + col], q);
    }
  }
}

// ---------------- MFMA GEMM stage 3 (K=128, N=256): SORTED y2 gather, y3 in slot order ----
__global__ __launch_bounds__(512, 4) void k_gemm3w(const unsigned short* __restrict__ X,
                                                   const float* __restrict__ acIn,
                                                   const float* __restrict__ W, const float* __restrict__ bias,
                                                   const int* __restrict__ sorted,
                                                   unsigned short* __restrict__ Y, float* __restrict__ stats,
                                                   int P) {
  // LDS: A [64][136] u16 17408 | Csm [64][264] u16 33792 | acL 2048 | bL 1024  = 54272
  __shared__ __align__(16) char smem[17408 + 33792 + 2048 + 1024];
  unsigned short* A   = (unsigned short*)smem;
  unsigned short* Csm = (unsigned short*)(smem + 17408);
  float* acL = (float*)(smem + 17408 + 33792);
  float* bL  = (float*)(smem + 17408 + 33792 + 2048);

  const int tid = threadIdx.x;
  for (int i = tid; i < 512; i += 512) acL[i] = acIn[i];
  if (tid < 256) bL[tid] = bias[tid];

  const int lane = tid & 63;
  const int w = tid >> 6;            // 8 waves
  const int li = lane & 15, lg = lane >> 4;
  const int cb = 32 * w;             // 8 * 32 = 256 cols

  // B fragments directly from global W (f32 [128][256]); one-time, L2-cached
  short8_t bfr[2][4];
#pragma unroll
  for (int t = 0; t < 2; ++t)
#pragma unroll
    for (int s = 0; s < 4; ++s) {
      int col = cb + 16 * t + li;
      int kb = 32 * s + 8 * lg;
      unsigned short tmp[8];
#pragma unroll
      for (int j = 0; j < 8; ++j) tmp[j] = f2bf(W[(size_t)(kb + j) * 256 + col]);
      bfr[t][s] = *(const short8_t*)tmp;
    }
  __syncthreads();  // acL/bL visible

  const int tiles = P >> 6;
  float sS[2] = {0.f, 0.f}, sQ[2] = {0.f, 0.f};
  uint4 pre[2];
  int tile = blockIdx.x;
  if (tile < tiles) {
#pragma unroll
    for (int it = 0; it < 2; ++it) {
      int i = tid + it * 512;                 // 0..1023 uint4 slots of 64x128 bf16 tile
      int row = i >> 4, seg = i & 15;
      int id = sorted[tile * 64 + row];       // broadcast (16 lanes share), L2-hot
      pre[it] = *(const uint4*)&X[(size_t)id * 128 + seg * 8];
    }
  }
  for (; tile < tiles; tile += gridDim.x) {
    const size_t row0 = (size_t)tile * 64;    // slot-order output rows
#pragma unroll
    for (int it = 0; it < 2; ++it) {
      int i = tid + it * 512;
      int row = i >> 4, seg = i & 15;
      const float* ap = &acL[seg * 8];
      const float* cp = &acL[256 + seg * 8];
      uint4 o;
      o.x = aff2(pre[it].x, ap[0], cp[0], ap[1], cp[1]);
      o.y = aff2(pre[it].y, ap[2], cp[2], ap[3], cp[3]);
      o.z = aff2(pre[it].z, ap[4], cp[4], ap[5], cp[5]);
      o.w = aff2(pre[it].w, ap[6], cp[6], ap[7], cp[7]);
      *(uint4*)&A[row * 136 + seg * 8] = o;
    }
    __syncthreads();  // B1
    int nt = tile + gridDim.x;
    if (nt < tiles) {
#pragma unroll
      for (int it = 0; it < 2; ++it) {
        int i = tid + it * 512;
        int row = i >> 4, seg = i & 15;
        int id = sorted[nt * 64 + row];
        pre[it] = *(const uint4*)&X[(size_t)id * 128 + seg * 8];
      }
    }

    floatx4 acc[4][2];
#pragma unroll
    for (int m = 0; m < 4; ++m)
#pragma unroll
      for (int t = 0; t < 2; ++t) acc[m][t] = (floatx4){0.f, 0.f, 0.f, 0.f};

#pragma unroll
    for (int s = 0; s < 4; ++s) {
      const int ko = 32 * s + 8 * lg;
      short8_t af0 = *(const short8_t*)&A[(li) * 136 + ko];
      short8_t af1 = *(const short8_t*)&A[(16 + li) * 136 + ko];
      short8_t af2 = *(const short8_t*)&A[(32 + li) * 136 + ko];
      short8_t af3 = *(const short8_t*)&A[(48 + li) * 136 + ko];
      acc[0][0] = __builtin_amdgcn_mfma_f32_16x16x32_bf16(af0, bfr[0][s], acc[0][0], 0, 0, 0);
      acc[1][0] = __builtin_amdgcn_mfma_f32_16x16x32_bf16(af1, bfr[0][s], acc[1][0], 0, 0, 0);
      acc[2][0] = __builtin_amdgcn_mfma_f32_16x16x32_bf16(af2, bfr[0][s], acc[2][0], 0, 0, 0);
      acc[3][0] = __builtin_amdgcn_mfma_f32_16x16x32_bf16(af3, bfr[0][s], acc[3][0], 0, 0, 0);
      acc[0][1] = __builtin_amdgcn_mfma_f32_16x16x32_bf16(af0, bfr[1][s], acc[0][1], 0, 0, 0);
      acc[1][1] = __builtin_amdgcn_mfma_f32_16x16x32_bf16(af1, bfr[1][s], acc[1][1], 0, 0, 0);
      acc[2][1] = __builtin_amdgcn_mfma_f32_16x16x32_bf16(af2, bfr[1][s], acc[2][1], 0, 0, 0);
      acc[3][1] = __builtin_amdgcn_mfma_f32_16x16x32_bf16(af3, bfr[1][s], acc[3][1], 0, 0, 0);
    }

#pragma unroll
    for (int m = 0; m < 4; ++m)
#pragma unroll
      for (int t = 0; t < 2; ++t) {
        int col = cb + 16 * t + li;
        float bb = bL[col];
#pragma unroll
        for (int rp = 0; rp < 2; ++rp) {
          int rowc = 16 * m + 4 * lg + 2 * rp;
          float v0 = acc[m][t][2 * rp] + bb;
          float v1 = acc[m][t][2 * rp + 1] + bb;
          unsigned int u = pk2bf(v0, v1);
          Csm[rowc * 264 + col] = (unsigned short)(u & 0xFFFFu);
          Csm[(rowc + 1) * 264 + col] = (unsigned short)(u >> 16);
          sS[t] += v0 + v1;
          sQ[t] += v0 * v0 + v1 * v1;
        }
      }
    __syncthreads();  // B2
    for (int i = tid; i < 2048; i += 512) {
      int rowc = i >> 5, seg = i & 31;
      *(uint4*)&Y[(row0 + rowc) * 256 + seg * 8] = *(const uint4*)&Csm[rowc * 264 + seg * 8];
    }
  }

#pragma unroll
  for (int t = 0; t < 2; ++t) {
    float s = sS[t];
    s += __shfl_xor(s, 16);
    s += __shfl_xor(s, 32);
    float q = sQ[t];
    q += __shfl_xor(q, 16);
    q += __shfl_xor(q, 32);
    if (lane < 16) {
      int col = cb + 16 * t + li;
      atomicAdd(&stats[col], s);
      atomicAdd(&stats[256 + col], q);
    }
  }
}

// ---------------- MFMA GEMM stage 4 (K=256, N=64): SEQUENTIAL slot-order reads, pipelined ----
__global__ __launch_bounds__(256, 4) void k_gemm4(const unsigned short* __restrict__ y3,
                                                  const float* __restrict__ ac3,
                                                  const float* __restrict__ W4, const float* __restrict__ b4,
                                                  unsigned short* __restrict__ h4, int P) {
  __shared__ __align__(16) char smem[34816 + 2048 + 256];
  unsigned short* A0 = (unsigned short*)smem;
  unsigned short* A1 = (unsigned short*)(smem + 17408);
  unsigned short* WTt = (unsigned short*)smem;  // transient
  float* acL = (float*)(smem + 34816);
  float* bL  = (float*)(smem + 34816 + 2048);

  const int tid = threadIdx.x;
  for (int i = tid; i < 64 * 256; i += 256) {
    int k = i >> 6, n = i & 63;
    WTt[n * 264 + k] = f2bf(W4[(size_t)k * 64 + n]);
  }
  for (int i = tid; i < 512; i += 256) acL[i] = ac3[i];
  if (tid < 64) bL[tid] = b4[tid];
  __syncthreads();

  const int lane = tid & 63;
  const int w = tid >> 6;
  const int li = lane & 15, lg = lane >> 4;
  const int cb = 16 * w;
  const int tiles = P >> 6;

  short8_t bfr[8];
#pragma unroll
  for (int s = 0; s < 8; ++s)
    bfr[s] = *(const short8_t*)&WTt[(cb + li) * 264 + 32 * s + 8 * lg];
  __syncthreads();  // WTt dead

  int tb = blockIdx.x;
  if (tb >= tiles) return;

  uint4 preA[4], preB[4];
#pragma unroll
  for (int it = 0; it < 4; ++it) {  // chunk0 of first tile
    int i = tid + it * 256;
    int row = i >> 4, seg = i & 15;
    preA[it] = *(const uint4*)&y3[((size_t)tb * 64 + row) * 256 + seg * 8];
  }

  for (; tb < tiles; tb += gridDim.x) {
    int nt = tb + gridDim.x;

    // stage chunk0
#pragma unroll
    for (int it = 0; it < 4; ++it) {
      int i = tid + it * 256;
      int row = i >> 4, seg = i & 15;
      const float* ap = &acL[seg * 8];
      const float* cp = &acL[256 + seg * 8];
      uint4 o;
      o.x = aff2(preA[it].x, ap[0], cp[0], ap[1], cp[1]);
      o.y = aff2(preA[it].y, ap[2], cp[2], ap[3], cp[3]);
      o.z = aff2(preA[it].z, ap[4], cp[4], ap[5], cp[5]);
      o.w = aff2(preA[it].w, ap[6], cp[6], ap[7], cp[7]);
      *(uint4*)&A0[row * 136 + seg * 8] = o;
    }
    __syncthreads();  // B1

    // issue chunk1 loads (contiguous rows)
#pragma unroll
    for (int it = 0; it < 4; ++it) {
      int i = tid + it * 256;
      int row = i >> 4, seg = i & 15;
      preB[it] = *(const uint4*)&y3[((size_t)tb * 64 + row) * 256 + 128 + seg * 8];
    }

    floatx4 acc[4];
#pragma unroll
    for (int m = 0; m < 4; ++m) acc[m] = (floatx4){0.f, 0.f, 0.f, 0.f};

#pragma unroll
    for (int s = 0; s < 4; ++s) {  // chunk0 MFMA
      const int ko = 32 * s + 8 * lg;
      short8_t af0 = *(const short8_t*)&A0[(li) * 136 + ko];
      short8_t af1 = *(const short8_t*)&A0[(16 + li) * 136 + ko];
      short8_t af2 = *(const short8_t*)&A0[(32 + li) * 136 + ko];
      short8_t af3 = *(const short8_t*)&A0[(48 + li) * 136 + ko];
      acc[0] = __builtin_amdgcn_mfma_f32_16x16x32_bf16(af0, bfr[s], acc[0], 0, 0, 0);
      acc[1] = __builtin_amdgcn_mfma_f32_16x16x32_bf16(af1, bfr[s], acc[1], 0, 0, 0);
      acc[2] = __builtin_amdgcn_mfma_f32_16x16x32_bf16(af2, bfr[s], acc[2], 0, 0, 0);
      acc[3] = __builtin_amdgcn_mfma_f32_16x16x32_bf16(af3, bfr[s], acc[3], 0, 0, 0);
    }
    __syncthreads();  // B2

    // stage chunk1
#pragma unroll
    for (int it = 0; it < 4; ++it) {
      int i = tid + it * 256;
      int row = i >> 4, seg = i & 15;
      const float* ap = &acL[128 + seg * 8];
      const float* cp = &acL[256 + 128 + seg * 8];
      uint4 o;
      o.x = aff2(preB[it].x, ap[0], cp[0], ap[1], cp[1]);
      o.y = aff2(preB[it].y, ap[2], cp[2], ap[3], cp[3]);
      o.z = aff2(preB[it].z, ap[4], cp[4], ap[5], cp[5]);
      o.w = aff2(preB[it].w, ap[6], cp[6], ap[7], cp[7]);
      *(uint4*)&A1[row * 136 + seg * 8] = o;
    }
    __syncthreads();  // B3

    if (nt < tiles) {  // issue chunk0 loads of next tile (contiguous)
#pragma unroll
      for (int it = 0; it < 4; ++it) {
        int i = tid + it * 256;
        int row = i >> 4, seg = i & 15;
        preA[it] = *(const uint4*)&y3[((size_t)nt * 64 + row) * 256 + seg * 8];
      }
    }

#pragma unroll
    for (int s = 0; s < 4; ++s) {  // chunk1 MFMA
      const int ko = 32 * s + 8 * lg;
      short8_t af0 = *(const short8_t*)&A1[(li) * 136 + ko];
      short8_t af1 = *(const short8_t*)&A1[(16 + li) * 136 + ko];
      short8_t af2 = *(const short8_t*)&A1[(32 + li) * 136 + ko];
      short8_t af3 = *(const short8_t*)&A1[(48 + li) * 136 + ko];
      acc[0] = __builtin_amdgcn_mfma_f32_16x16x32_bf16(af0, bfr[4 + s], acc[0], 0, 0, 0);
      acc[1] = __builtin_amdgcn_mfma_f32_16x16x32_bf16(af1, bfr[4 + s], acc[1], 0, 0, 0);
      acc[2] = __builtin_amdgcn_mfma_f32_16x16x32_bf16(af2, bfr[4 + s], acc[2], 0, 0, 0);
      acc[3] = __builtin_amdgcn_mfma_f32_16x16x32_bf16(af3, bfr[4 + s], acc[3], 0, 0, 0);
    }
    __syncthreads();  // B4 — A1 consumed by all waves; Csm may alias

    unsigned short* Csm = A1;  // [64][72]
    {
      int col = cb + li;
      float bb = bL[col];
#pragma unroll
      for (int m = 0; m < 4; ++m)
#pragma unroll
        for (int rp = 0; rp < 2; ++rp) {
          int rowc = 16 * m + 4 * lg + 2 * rp;
          unsigned int u = pk2bf(acc[m][2 * rp] + bb, acc[m][2 * rp + 1] + bb);
          Csm[rowc * 72 + col] = (unsigned short)(u & 0xFFFFu);
          Csm[(rowc + 1) * 72 + col] = (unsigned short)(u >> 16);
        }
    }
    __syncthreads();  // B5
    for (int i = tid; i < 512; i += 256) {
      int rowc = i >> 3, seg = i & 7;
      *(uint4*)&h4[(size_t)(tb * 64 + rowc) * 64 + seg * 8] = *(const uint4*)&Csm[rowc * 72 + seg * 8];
    }
  }
}

// ---------------- gather-mean: 8 consecutive ranks per wave (8-way MLP) ----------------
__global__ __launch_bounds__(256) void k_gather(const unsigned short* __restrict__ h4,
                                                const int2* __restrict__ rankCS,
                                                float* __restrict__ outp, int P) {
  int wv = threadIdx.x >> 6;
  int j = threadIdx.x & 63;
  int r0 = blockIdx.x * 32 + wv * 8;
  if (r0 >= P) return;
  int cnt[8], st[8];
  int maxc = 0;
#pragma unroll
  for (int i = 0; i < 8; ++i) {
    int2 cs = (r0 + i < P) ? rankCS[r0 + i] : make_int2(0, 0);
    cnt[i] = cs.x;
    st[i] = cs.y;
    maxc = max(maxc, cs.x);
  }
  float acc[8] = {};
  for (int k = 0; k < maxc; ++k) {
#pragma unroll
    for (int i = 0; i < 8; ++i)
      if (k < cnt[i]) acc[i] += bf2f(h4[(size_t)(st[i] + k) * 64 + j]);
  }
#pragma unroll
  for (int i = 0; i < 8; ++i)
    if (r0 + i < P) outp[(size_t)(r0 + i) * 64 + j] = (cnt[i] > 0) ? acc[i] / (float)cnt[i] : 0.f;
}

// ---------------- launch ----------------

extern "C" void kernel_launch(void* const* d_in, const int* in_sizes, int n_in,
                              void* d_out, int out_size, void* d_ws, size_t ws_size,
                              hipStream_t stream) {
  const float* pt_fea = (const float*)d_in[0];
  const int*   xy     = (const int*)d_in[1];
  const float* bn0_g = (const float*)d_in[2];
  const float* bn0_b = (const float*)d_in[3];
  const float* W1 = (const float*)d_in[4];
  const float* b1 = (const float*)d_in[5];
  const float* bn1_g = (const float*)d_in[6];
  const float* bn1_b = (const float*)d_in[7];
  const float* W2 = (const float*)d_in[8];
  const float* b2 = (const float*)d_in[9];
  const float* bn2_g = (const float*)d_in[10];
  const float* bn2_b = (const float*)d_in[11];
  const float* W3 = (const float*)d_in[12];
  const float* b3 = (const float*)d_in[13];
  const float* bn3_g = (const float*)d_in[14];
  const float* bn3_b = (const float*)d_in[15];
  const float* W4 = (const float*)d_in[16];
  const float* b4 = (const float*)d_in[17];

  const int P = in_sizes[0] / 9;  // 400000
  const int Nhalf = P / 2;

  char* w = (char*)d_ws;
  size_t off = 0;
  auto alloc = [&](size_t bytes) -> void* {
    off = (off + 255) & ~(size_t)255;
    void* p = w + off;
    off += bytes;
    return p;
  };
  int* counts    = (int*)alloc((size_t)NKEYS * 4);
  int* prefix    = (int*)alloc((size_t)NKEYS * 4);
  int* prefixS   = (int*)alloc((size_t)NKEYS * 4);
  int* blockTot  = (int*)alloc(512 * 4);
  int* blockOff  = (int*)alloc(512 * 4);
  int* blockTotS = (int*)alloc(512 * 4);
  int* blockOffS = (int*)alloc(512 * 4);
  int* dU        = (int*)alloc(256);
  int* flag      = (int*)alloc(256);
  int2* rankCS   = (int2*)alloc((size_t)P * 8);
  int* sorted    = (int*)alloc((size_t)P * 4);
  float* partials = (float*)alloc((size_t)2 * SQOFF * 4);
  float* st1 = (float*)alloc(512 * 4);
  float* st2 = (float*)alloc(512 * 4);
  float* st3 = (float*)alloc(512 * 4);
  float* ac0 = (float*)alloc(512 * 4);
  float* ac1 = (float*)alloc(512 * 4);
  float* ac2 = (float*)alloc(512 * 4);
  float* ac3 = (float*)alloc(512 * 4);
  unsigned short* y1 = (unsigned short*)alloc((size_t)P * 64 * 2);   // reused for h4
  unsigned short* y2 = (unsigned short*)alloc((size_t)P * 128 * 2);
  unsigned short* y3 = (unsigned short*)alloc((size_t)P * 256 * 2);  // slot-ordered
  (void)ws_size; (void)n_in; (void)out_size;
  // peak ws ~= 368 MB (r6-r20 footprint ran cleanly)

  float* out_unq = (float*)d_out;               // f32 (P,3)
  float* out_pooled = out_unq + (size_t)P * 3;  // f32 (P,64)

  const int nbP = (P + 255) / 256;

  // ---- unique + sort pipeline (fused scans / fill+pad; cursor & rankCS zeroing folded in) ----
  hipMemsetAsync(counts, 0, (size_t)NKEYS * 4, stream);
  hipMemsetAsync(st1, 0, 3 * 2048, stream);  // st1,st2,st3 contiguous
  k_detect<<<1, 1024, 0, stream>>>(xy, flag);
  k_count<<<nbP, 256, 0, stream>>>(xy, flag, counts, P, Nhalf);
  k_scan1b<<<SCAN_NB, 256, 0, stream>>>(counts, prefix, prefixS, blockTot, blockTotS);
  k_scan2b<<<2, 512, 0, stream>>>(blockTot, blockTotS, blockOff, blockOffS, dU);
  k_fillpad<<<nbP, 256, 0, stream>>>(counts, prefix, blockOff, prefixS, blockOffS, dU,
                                     out_unq, rankCS, P);
  k_sortpts<<<nbP, 256, 0, stream>>>(xy, flag, prefixS, blockOffS, counts, sorted, P, Nhalf);

  // ---- MLP ----
  k_stats9<<<STATS_NBLK, 256, 0, stream>>>(pt_fea, P, partials);
  k_finalize<<<1, 9, 0, stream>>>(partials, bn0_g, bn0_b, ac0, 9, P);

  k_stage1s<<<2048, 256, 0, stream>>>(pt_fea, ac0, W1, b1, y1, st1, P);
  k_finalize_at<<<1, 64, 0, stream>>>(st1, bn1_g, bn1_b, ac1, 64, P);

  k_gemmM<64><<<dim3(2048, 1), 256, 0, stream>>>(y1, ac1, W2, b2, y2, st2, 128, P);
  k_finalize_at<<<1, 128, 0, stream>>>(st2, bn2_g, bn2_b, ac2, 128, P);

  // stage 3 gathers y2 via sorted (256B rows, mostly L3-resident); y3 written slot-ordered
  k_gemm3w<<<1024, 512, 0, stream>>>(y2, ac2, W3, b3, sorted, y3, st3, P);
  k_finalize_at<<<1, 256, 0, stream>>>(st3, bn3_g, bn3_b, ac3, 256, P);

  // stage 4 fully sequential over slot-ordered y3 -> h4 in slot order
  unsigned short* h4 = y1;  // y1 free after gemmM<64>
  k_gemm4<<<2048, 256, 0, stream>>>(y3, ac3, W4, b4, h4, P);

  // ---- gather mean (8 consecutive ranks per wave; slots contiguous) ----
  k_gather<<<(P + 31) / 32, 256, 0, stream>>>(h4, rankCS, out_pooled, P);
}

// Round 22
// 392.273 us; speedup vs baseline: 1.0048x; 1.0048x over previous
//
#include <hip/hip_runtime.h>
#include <hip/hip_bf16.h>

#define GXGY 172800   // 480*360
#define GYC  360
#define NKEYS 345600  // 2*GXGY  (B=2)
#define SCAN_NB 338   // ceil(345600/1024)
#define STATS_NBLK 256
#define SQOFF 65536   // partials sumsq offset (floats)

typedef short short8_t __attribute__((ext_vector_type(8)));
typedef float floatx4 __attribute__((ext_vector_type(4)));

// ---------------- bf16 helpers ----------------
__device__ inline float bf2f(unsigned short u) {
  union { unsigned int i; float f; } v;
  v.i = ((unsigned int)u) << 16;
  return v.f;
}
__device__ inline unsigned short f2bf(float f) {
  union { float f; unsigned int i; } v;
  v.f = f;
  unsigned int lsb = (v.i >> 16) & 1u;
  return (unsigned short)((v.i + 0x7FFFu + lsb) >> 16);  // RNE (cold paths)
}
// HW packed RNE conversion: 2 f32 -> packed bf16x2 (v_cvt_pk_bf16_f32), lo = a
__device__ inline unsigned int pk2bf(float lo, float hi) {
  __hip_bfloat162 h = __float22bfloat162_rn(float2{lo, hi});
  union { __hip_bfloat162 h; unsigned int u; } c;
  c.h = h;
  return c.u;
}
// affine+relu two packed bf16 -> packed bf16 (hot path, HW cvt_pk)
__device__ inline unsigned int aff2(unsigned int pr, float a0, float c0, float a1, float c1) {
  union { unsigned int i; float f; } t0, t1;
  t0.i = pr << 16; t1.i = pr & 0xFFFF0000u;
  float v0 = fmaxf(fmaf(t0.f, a0, c0), 0.f);
  float v1 = fmaxf(fmaf(t1.f, a1, c1), 0.f);
  return pk2bf(v0, v1);
}

// ---------------- xy dtype probe: int32 pairs vs int64 ----------------
__global__ __launch_bounds__(1024) void k_detect(const int* __restrict__ xy, int* __restrict__ flag) {
  __shared__ int any;
  if (threadIdx.x == 0) any = 0;
  __syncthreads();
  if (xy[threadIdx.x * 2 + 1] != 0) atomicOr(&any, 1);
  __syncthreads();
  if (threadIdx.x == 0) *flag = any;  // 1 -> int32, 0 -> int64
}

__device__ inline void load_xy(const int* xy, const int* flag, int p, int& ix, int& iy) {
  if (*flag) { ix = xy[(size_t)p * 2]; iy = xy[(size_t)p * 2 + 1]; }
  else       { ix = xy[(size_t)p * 4]; iy = xy[(size_t)p * 4 + 2]; }
}

// ---------------- unique via dense histogram + scans ----------------

__global__ __launch_bounds__(256) void k_count(const int* __restrict__ xy, const int* __restrict__ flag,
                                               int* __restrict__ counts, int P, int N) {
  int p = blockIdx.x * 256 + threadIdx.x;
  if (p >= P) return;
  int ix, iy;
  load_xy(xy, flag, p, ix, iy);
  int key = ((p >= N) ? GXGY : 0) + ix * GYC + iy;
  atomicAdd(&counts[key], 1);
}

// fused dual scan: occupancy flags -> prefix, counts -> prefixS (one counts read)
__global__ __launch_bounds__(256) void k_scan1b(const int* __restrict__ counts,
                                                int* __restrict__ prefix, int* __restrict__ prefixS,
                                                int* __restrict__ blockTot, int* __restrict__ blockTotS) {
  __shared__ int sf[256], sv[256];
  int base = blockIdx.x * 1024;
  int f[4], c[4];
  int tf = 0, tv = 0;
#pragma unroll
  for (int i = 0; i < 4; ++i) {
    int k = base + threadIdx.x * 4 + i;
    int cnt = (k < NKEYS) ? counts[k] : 0;
    c[i] = cnt;
    f[i] = (cnt > 0) ? 1 : 0;
    tf += f[i];
    tv += c[i];
  }
  sf[threadIdx.x] = tf;
  sv[threadIdx.x] = tv;
  __syncthreads();
  for (int off = 1; off < 256; off <<= 1) {
    int a = (threadIdx.x >= off) ? sf[threadIdx.x - off] : 0;
    int b = (threadIdx.x >= off) ? sv[threadIdx.x - off] : 0;
    __syncthreads();
    if (threadIdx.x >= off) {
      sf[threadIdx.x] += a;
      sv[threadIdx.x] += b;
    }
    __syncthreads();
  }
  int runF = (threadIdx.x == 0) ? 0 : sf[threadIdx.x - 1];
  int runV = (threadIdx.x == 0) ? 0 : sv[threadIdx.x - 1];
#pragma unroll
  for (int i = 0; i < 4; ++i) {
    int k = base + threadIdx.x * 4 + i;
    if (k < NKEYS) {
      prefix[k] = runF;
      prefixS[k] = runV;
    }
    runF += f[i];
    runV += c[i];
  }
  if (threadIdx.x == 255) {
    blockTot[blockIdx.x] = sf[255];
    blockTotS[blockIdx.x] = sv[255];
  }
}

// fused pair of block-level scans: block 0 -> blockOff(+dU), block 1 -> blockOffS
__global__ __launch_bounds__(512) void k_scan2b(const int* __restrict__ blockTot,
                                                const int* __restrict__ blockTotS,
                                                int* __restrict__ blockOff, int* __restrict__ blockOffS,
                                                int* __restrict__ dU) {
  __shared__ int s[512];
  const int* in = (blockIdx.x == 0) ? blockTot : blockTotS;
  int* out = (blockIdx.x == 0) ? blockOff : blockOffS;
  int v = (threadIdx.x < SCAN_NB) ? in[threadIdx.x] : 0;
  s[threadIdx.x] = v;
  __syncthreads();
  for (int off = 1; off < 512; off <<= 1) {
    int t = (threadIdx.x >= off) ? s[threadIdx.x - off] : 0;
    __syncthreads();
    if (threadIdx.x >= off) s[threadIdx.x] += t;
    __syncthreads();
  }
  if (threadIdx.x < SCAN_NB) out[threadIdx.x] = s[threadIdx.x] - v;  // exclusive
  if (blockIdx.x == 0 && threadIdx.x == 511) *dU = s[511];
}

// fused fillunq + pad + cursor-reset + rankCS pad-zero (grid covers P >= NKEYS)
__global__ __launch_bounds__(256) void k_fillpad(int* __restrict__ counts, const int* __restrict__ prefix,
                                                 const int* __restrict__ blockOff,
                                                 const int* __restrict__ prefixS, const int* __restrict__ blockOffS,
                                                 const int* __restrict__ dU,
                                                 float* __restrict__ out_unq, int2* __restrict__ rankCS, int P) {
  int i = blockIdx.x * 256 + threadIdx.x;
  if (i < NKEYS) {
    int cnt = counts[i];
    if (cnt > 0) {
      counts[i] = 0;  // cursor reset for k_sortpts
      int r = prefix[i] + blockOff[i >> 10];
      rankCS[r] = make_int2(cnt, prefixS[i] + blockOffS[i >> 10]);
      int b = i / GXGY;
      int rem = i % GXGY;
      out_unq[(size_t)r * 3 + 0] = (float)b;
      out_unq[(size_t)r * 3 + 1] = (float)(rem / GYC);
      out_unq[(size_t)r * 3 + 2] = (float)(rem % GYC);
    }
  }
  if (i < P && i >= *dU) {  // pad ranks: key=-1 -> (-1, 479, 359); zero (cnt,start)
    out_unq[(size_t)i * 3 + 0] = -1.f;
    out_unq[(size_t)i * 3 + 1] = 479.f;
    out_unq[(size_t)i * 3 + 2] = 359.f;
    rankCS[i] = make_int2(0, 0);
  }
}

// counting sort: slot = keyStart + cursor (counts reused as cursor, reset by k_fillpad)
__global__ __launch_bounds__(256) void k_sortpts(const int* __restrict__ xy, const int* __restrict__ flag,
                                                 const int* __restrict__ prefixS,
                                                 const int* __restrict__ blockOffS, int* __restrict__ cursor,
                                                 int* __restrict__ sorted, int P, int N) {
  int p = blockIdx.x * 256 + threadIdx.x;
  if (p >= P) return;
  int ix, iy;
  load_xy(xy, flag, p, ix, iy);
  int key = ((p >= N) ? GXGY : 0) + ix * GYC + iy;
  int slot = prefixS[key] + blockOffS[key >> 10] + atomicAdd(&cursor[key], 1);
  sorted[slot] = p;
}

// ---------------- BN0 stats + finalize ----------------

__global__ __launch_bounds__(256) void k_stats9(const float* __restrict__ x, int P, float* __restrict__ partials) {
  float s[9] = {0}, q[9] = {0};
  for (int p = blockIdx.x * 256 + threadIdx.x; p < P; p += STATS_NBLK * 256) {
#pragma unroll
    for (int k = 0; k < 9; ++k) {
      float v = x[(size_t)p * 9 + k];
      s[k] += v;
      q[k] += v * v;
    }
  }
  __shared__ float ls[256 * 9];
#pragma unroll
  for (int k = 0; k < 9; ++k) ls[threadIdx.x * 9 + k] = s[k];
  __syncthreads();
  if (threadIdx.x < 9) {
    float acc = 0;
    for (int t = 0; t < 256; ++t) acc += ls[t * 9 + threadIdx.x];
    partials[blockIdx.x * 9 + threadIdx.x] = acc;
  }
  __syncthreads();
#pragma unroll
  for (int k = 0; k < 9; ++k) ls[threadIdx.x * 9 + k] = q[k];
  __syncthreads();
  if (threadIdx.x < 9) {
    float acc = 0;
    for (int t = 0; t < 256; ++t) acc += ls[t * 9 + threadIdx.x];
    partials[SQOFF + blockIdx.x * 9 + threadIdx.x] = acc;
  }
}

__global__ void k_finalize(const float* __restrict__ partials, const float* __restrict__ gam,
                           const float* __restrict__ bet, float* __restrict__ ac, int F, int P) {
  int f = threadIdx.x;
  if (f >= F) return;
  float s = 0.f, q = 0.f;
  for (int blk = 0; blk < STATS_NBLK; ++blk) {
    s += partials[blk * F + f];
    q += partials[SQOFF + blk * F + f];
  }
  float mean = s / (float)P;
  float var = q / (float)P - mean * mean;
  float A = gam[f] * rsqrtf(var + 1e-5f);
  ac[f] = A;
  ac[256 + f] = bet[f] - mean * A;
}

__global__ void k_finalize_at(const float* __restrict__ stats, const float* __restrict__ gam,
                              const float* __restrict__ bet, float* __restrict__ ac, int F, int P) {
  int f = threadIdx.x;
  if (f >= F) return;
  float mean = stats[f] / (float)P;
  float var = stats[256 + f] / (float)P - mean * mean;
  float A = gam[f] * rsqrtf(var + 1e-5f);
  ac[f] = A;
  ac[256 + f] = bet[f] - mean * A;
}

// ---------------- stage 1 (K=9): tiled/vectorized + fused BN1 stats ----------------
__global__ __launch_bounds__(256) void k_stage1s(const float* __restrict__ x, const float* __restrict__ ac,
                                                 const float* __restrict__ W1, const float* __restrict__ b1,
                                                 unsigned short* __restrict__ y1, float* __restrict__ stats,
                                                 int P) {
  __shared__ float sW[576];
  __shared__ float sb[64];
  __shared__ float sa[9], sc[9];
  __shared__ float xT[288];
  __shared__ float gS[256], gQ[256];
  const int tid = threadIdx.x;
  for (int i = tid; i < 576; i += 256) sW[i] = W1[i];
  if (tid < 64) sb[tid] = b1[tid];
  if (tid < 9) {
    sa[tid] = ac[tid];
    sc[tid] = ac[256 + tid];
  }
  const int row_l = tid >> 3;   // 0..31
  const int cg = tid & 7;       // col group (8 cols)
  const int tiles = P >> 5;     // P % 32 == 0
  float sS[8] = {}, sQ[8] = {};
  float pre0 = 0.f, pre1 = 0.f;
  int tile = blockIdx.x;
  if (tile < tiles) {
    size_t base = (size_t)tile * 288;
    pre0 = x[base + tid];
    if (tid < 32) pre1 = x[base + 256 + tid];
  }
  __syncthreads();
  for (; tile < tiles; tile += gridDim.x) {
    xT[tid] = pre0;
    if (tid < 32) xT[256 + tid] = pre1;
    __syncthreads();
    int nt = tile + gridDim.x;
    if (nt < tiles) {
      size_t base = (size_t)nt * 288;
      pre0 = x[base + tid];
      if (tid < 32) pre1 = x[base + 256 + tid];
    }
    float acc[8];
#pragma unroll
    for (int c = 0; c < 8; ++c) acc[c] = sb[cg * 8 + c];
#pragma unroll
    for (int k = 0; k < 9; ++k) {
      float xn = fmaf(xT[row_l * 9 + k], sa[k], sc[k]);
#pragma unroll
      for (int c = 0; c < 8; ++c) acc[c] = fmaf(xn, sW[k * 64 + cg * 8 + c], acc[c]);
    }
    uint4 o;
    o.x = pk2bf(acc[0], acc[1]);
    o.y = pk2bf(acc[2], acc[3]);
    o.z = pk2bf(acc[4], acc[5]);
    o.w = pk2bf(acc[6], acc[7]);
    *(uint4*)&y1[((size_t)tile * 32 + row_l) * 64 + cg * 8] = o;
#pragma unroll
    for (int c = 0; c < 8; ++c) {
      sS[c] += acc[c];
      sQ[c] += acc[c] * acc[c];
    }
    __syncthreads();  // xT consumed before next overwrite
  }
#pragma unroll
  for (int c = 0; c < 8; ++c) {
    sS[c] += __shfl_xor(sS[c], 8);
    sS[c] += __shfl_xor(sS[c], 16);
    sS[c] += __shfl_xor(sS[c], 32);
    sQ[c] += __shfl_xor(sQ[c], 8);
    sQ[c] += __shfl_xor(sQ[c], 16);
    sQ[c] += __shfl_xor(sQ[c], 32);
  }
  int lane = tid & 63, wv = tid >> 6;
  if (lane < 8) {
#pragma unroll
    for (int c = 0; c < 8; ++c) {
      gS[wv * 64 + lane * 8 + c] = sS[c];
      gQ[wv * 64 + lane * 8 + c] = sQ[c];
    }
  }
  __syncthreads();
  if (tid < 64) {
    float S = gS[tid] + gS[64 + tid] + gS[128 + tid] + gS[192 + tid];
    float Q = gQ[tid] + gQ[64 + tid] + gQ[128 + tid] + gQ[192 + tid];
    atomicAdd(&stats[tid], S);
    atomicAdd(&stats[256 + tid], Q);
  }
}

// ---------------- MFMA GEMM stage 2 (K=64, N=128) ----------------
template <int K>
__global__ __launch_bounds__(256, 4) void k_gemmM(const unsigned short* __restrict__ X,
                                                  const float* __restrict__ acIn,
                                                  const float* __restrict__ W, const float* __restrict__ bias,
                                                  unsigned short* __restrict__ Y, float* __restrict__ stats,
                                                  int N, int P) {
  constexpr int SEGS = K / 8;
  constexpr int NIT = K / 32;          // uint4 staging regs per thread
  constexpr int KPA = K + 8;           // A / W^T row stride (u16)
  constexpr int OFF_C = 64 * KPA * 2;  // Csm after A
  constexpr int OFF_AC = OFF_C + 64 * 136 * 2;
  constexpr int OFF_B = OFF_AC + 512 * 4;
  constexpr int SMEM = OFF_B + 128 * 4;
  static_assert(64 * KPA * 2 + 64 * 136 * 2 >= 128 * KPA * 2, "WTtmp alias fits in A+Csm");
  __shared__ __align__(16) char smem[SMEM];
  unsigned short* A   = (unsigned short*)smem;             // [64][KPA]
  unsigned short* Csm = (unsigned short*)(smem + OFF_C);   // [64][136]
  unsigned short* WTt = (unsigned short*)smem;             // transient [128][KPA], aliases A+Csm
  float* acL = (float*)(smem + OFF_AC);
  float* bL  = (float*)(smem + OFF_B);

  const int tid = threadIdx.x;
  const int nq = blockIdx.y;

  for (int i = tid; i < 128 * K; i += 256) {
    int k = i >> 7, n = i & 127;
    WTt[n * KPA + k] = f2bf(W[(size_t)k * N + nq * 128 + n]);
  }
  for (int i = tid; i < 512; i += 256) acL[i] = acIn[i];
  if (tid < 128) bL[tid] = bias[nq * 128 + tid];
  __syncthreads();

  const int lane = tid & 63;
  const int w = tid >> 6;
  const int li = lane & 15, lg = lane >> 4;
  const int cb = 32 * w;

  short8_t bfr[2][K / 32];
#pragma unroll
  for (int t = 0; t < 2; ++t)
#pragma unroll
    for (int s = 0; s < K / 32; ++s)
      bfr[t][s] = *(const short8_t*)&WTt[(cb + 16 * t + li) * KPA + 32 * s + 8 * lg];
  __syncthreads();  // WTt dead; A/Csm live from here

  const int tiles = P >> 6;
  float sS[2] = {0.f, 0.f}, sQ[2] = {0.f, 0.f};
  uint4 pre[NIT];
  int tile = blockIdx.x;
  if (tile < tiles) {
#pragma unroll
    for (int it = 0; it < NIT; ++it) {
      int i = tid + it * 256;
      int row = i / SEGS, seg = i % SEGS;
      pre[it] = *(const uint4*)&X[((size_t)tile * 64 + row) * K + seg * 8];
    }
  }
  for (; tile < tiles; tile += gridDim.x) {
    const size_t row0 = (size_t)tile * 64;
#pragma unroll
    for (int it = 0; it < NIT; ++it) {
      int i = tid + it * 256;
      int row = i / SEGS, seg = i % SEGS;
      const float* ap = &acL[seg * 8];
      const float* cp = &acL[256 + seg * 8];
      uint4 o;
      o.x = aff2(pre[it].x, ap[0], cp[0], ap[1], cp[1]);
      o.y = aff2(pre[it].y, ap[2], cp[2], ap[3], cp[3]);
      o.z = aff2(pre[it].z, ap[4], cp[4], ap[5], cp[5]);
      o.w = aff2(pre[it].w, ap[6], cp[6], ap[7], cp[7]);
      *(uint4*)&A[row * KPA + seg * 8] = o;
    }
    __syncthreads();  // B1
    int nt = tile + gridDim.x;
    if (nt < tiles) {
#pragma unroll
      for (int it = 0; it < NIT; ++it) {
        int i = tid + it * 256;
        int row = i / SEGS, seg = i % SEGS;
        pre[it] = *(const uint4*)&X[((size_t)nt * 64 + row) * K + seg * 8];
      }
    }

    floatx4 acc[4][2];
#pragma unroll
    for (int m = 0; m < 4; ++m)
#pragma unroll
      for (int t = 0; t < 2; ++t) acc[m][t] = (floatx4){0.f, 0.f, 0.f, 0.f};

#pragma unroll
    for (int s = 0; s < K / 32; ++s) {
      const int ko = 32 * s + 8 * lg;
      short8_t af0 = *(const short8_t*)&A[(li) * KPA + ko];
      short8_t af1 = *(const short8_t*)&A[(16 + li) * KPA + ko];
      short8_t af2 = *(const short8_t*)&A[(32 + li) * KPA + ko];
      short8_t af3 = *(const short8_t*)&A[(48 + li) * KPA + ko];
      acc[0][0] = __builtin_amdgcn_mfma_f32_16x16x32_bf16(af0, bfr[0][s], acc[0][0], 0, 0, 0);
      acc[1][0] = __builtin_amdgcn_mfma_f32_16x16x32_bf16(af1, bfr[0][s], acc[1][0], 0, 0, 0);
      acc[2][0] = __builtin_amdgcn_mfma_f32_16x16x32_bf16(af2, bfr[0][s], acc[2][0], 0, 0, 0);
      acc[3][0] = __builtin_amdgcn_mfma_f32_16x16x32_bf16(af3, bfr[0][s], acc[3][0], 0, 0, 0);
      acc[0][1] = __builtin_amdgcn_mfma_f32_16x16x32_bf16(af0, bfr[1][s], acc[0][1], 0, 0, 0);
      acc[1][1] = __builtin_amdgcn_mfma_f32_16x16x32_bf16(af1, bfr[1][s], acc[1][1], 0, 0, 0);
      acc[2][1] = __builtin_amdgcn_mfma_f32_16x16x32_bf16(af2, bfr[1][s], acc[2][1], 0, 0, 0);
      acc[3][1] = __builtin_amdgcn_mfma_f32_16x16x32_bf16(af3, bfr[1][s], acc[3][1], 0, 0, 0);
    }

#pragma unroll
    for (int m = 0; m < 4; ++m)
#pragma unroll
      for (int t = 0; t < 2; ++t) {
        int col = cb + 16 * t + li;
        float bb = bL[col];
#pragma unroll
        for (int rp = 0; rp < 2; ++rp) {
          int rowc = 16 * m + 4 * lg + 2 * rp;
          float v0 = acc[m][t][2 * rp] + bb;
          float v1 = acc[m][t][2 * rp + 1] + bb;
          unsigned int u = pk2bf(v0, v1);
          Csm[rowc * 136 + col] = (unsigned short)(u & 0xFFFFu);
          Csm[(rowc + 1) * 136 + col] = (unsigned short)(u >> 16);
          sS[t] += v0 + v1;
          sQ[t] += v0 * v0 + v1 * v1;
        }
      }
    __syncthreads();  // B2
    for (int i = tid; i < 1024; i += 256) {
      int rowc = i >> 4, seg = i & 15;
      *(uint4*)&Y[(row0 + rowc) * N + nq * 128 + seg * 8] = *(const uint4*)&Csm[rowc * 136 + seg * 8];
    }
  }

#pragma unroll
  for (int t = 0; t < 2; ++t) {
    float s = sS[t];
    s += __shfl_xor(s, 16);
    s += __shfl_xor(s, 32);
    float q = sQ[t];
    q += __shfl_xor(q, 16);
    q += __shfl_xor(q, 32);
    if (lane < 16) {
      int col = nq * 128 + cb + 16 * t + li;
      atomicAdd(&stats[col], s);
      atomicAdd(&stats[256 + col], q);
    }
  }
}

// ---------------- MFMA GEMM stage 3 (K=128, N=256 FULL WIDTH): 512 thr, y2 read once ----
__global__ __launch_bounds__(512, 4) void k_gemm3w(const unsigned short* __restrict__ X,
                                                   const float* __restrict__ acIn,
                                                   const float* __restrict__ W, const float* __restrict__ bias,
                                                   unsigned short* __restrict__ Y, float* __restrict__ stats,
                                                   int P) {
  // LDS: A [64][136] u16 17408 | Csm [64][264] u16 33792 | acL 2048 | bL 1024  = 54272
  __shared__ __align__(16) char smem[17408 + 33792 + 2048 + 1024];
  unsigned short* A   = (unsigned short*)smem;
  unsigned short* Csm = (unsigned short*)(smem + 17408);
  float* acL = (float*)(smem + 17408 + 33792);
  float* bL  = (float*)(smem + 17408 + 33792 + 2048);

  const int tid = threadIdx.x;
  for (int i = tid; i < 512; i += 512) acL[i] = acIn[i];
  if (tid < 256) bL[tid] = bias[tid];

  const int lane = tid & 63;
  const int w = tid >> 6;            // 8 waves
  const int li = lane & 15, lg = lane >> 4;
  const int cb = 32 * w;             // 8 * 32 = 256 cols

  // B fragments directly from global W (f32 [128][256]); one-time, L2-cached
  short8_t bfr[2][4];
#pragma unroll
  for (int t = 0; t < 2; ++t)
#pragma unroll
    for (int s = 0; s < 4; ++s) {
      int col = cb + 16 * t + li;
      int kb = 32 * s + 8 * lg;
      unsigned short tmp[8];
#pragma unroll
      for (int j = 0; j < 8; ++j) tmp[j] = f2bf(W[(size_t)(kb + j) * 256 + col]);
      bfr[t][s] = *(const short8_t*)tmp;
    }
  __syncthreads();  // acL/bL visible

  const int tiles = P >> 6;
  float sS[2] = {0.f, 0.f}, sQ[2] = {0.f, 0.f};
  uint4 pre[2];
  int tile = blockIdx.x;
  if (tile < tiles) {
#pragma unroll
    for (int it = 0; it < 2; ++it) {
      int i = tid + it * 512;                 // 0..1023 uint4 slots of 64x128 bf16 tile
      int row = i >> 4, seg = i & 15;
      pre[it] = *(const uint4*)&X[((size_t)tile * 64 + row) * 128 + seg * 8];
    }
  }
  for (; tile < tiles; tile += gridDim.x) {
    const size_t row0 = (size_t)tile * 64;
#pragma unroll
    for (int it = 0; it < 2; ++it) {
      int i = tid + it * 512;
      int row = i >> 4, seg = i & 15;
      const float* ap = &acL[seg * 8];
      const float* cp = &acL[256 + seg * 8];
      uint4 o;
      o.x = aff2(pre[it].x, ap[0], cp[0], ap[1], cp[1]);
      o.y = aff2(pre[it].y, ap[2], cp[2], ap[3], cp[3]);
      o.z = aff2(pre[it].z, ap[4], cp[4], ap[5], cp[5]);
      o.w = aff2(pre[it].w, ap[6], cp[6], ap[7], cp[7]);
      *(uint4*)&A[row * 136 + seg * 8] = o;
    }
    __syncthreads();  // B1
    int nt = tile + gridDim.x;
    if (nt < tiles) {
#pragma unroll
      for (int it = 0; it < 2; ++it) {
        int i = tid + it * 512;
        int row = i >> 4, seg = i & 15;
        pre[it] = *(const uint4*)&X[((size_t)nt * 64 + row) * 128 + seg * 8];
      }
    }

    floatx4 acc[4][2];
#pragma unroll
    for (int m = 0; m < 4; ++m)
#pragma unroll
      for (int t = 0; t < 2; ++t) acc[m][t] = (floatx4){0.f, 0.f, 0.f, 0.f};

#pragma unroll
    for (int s = 0; s < 4; ++s) {
      const int ko = 32 * s + 8 * lg;
      short8_t af0 = *(const short8_t*)&A[(li) * 136 + ko];
      short8_t af1 = *(const short8_t*)&A[(16 + li) * 136 + ko];
      short8_t af2 = *(const short8_t*)&A[(32 + li) * 136 + ko];
      short8_t af3 = *(const short8_t*)&A[(48 + li) * 136 + ko];
      acc[0][0] = __builtin_amdgcn_mfma_f32_16x16x32_bf16(af0, bfr[0][s], acc[0][0], 0, 0, 0);
      acc[1][0] = __builtin_amdgcn_mfma_f32_16x16x32_bf16(af1, bfr[0][s], acc[1][0], 0, 0, 0);
      acc[2][0] = __builtin_amdgcn_mfma_f32_16x16x32_bf16(af2, bfr[0][s], acc[2][0], 0, 0, 0);
      acc[3][0] = __builtin_amdgcn_mfma_f32_16x16x32_bf16(af3, bfr[0][s], acc[3][0], 0, 0, 0);
      acc[0][1] = __builtin_amdgcn_mfma_f32_16x16x32_bf16(af0, bfr[1][s], acc[0][1], 0, 0, 0);
      acc[1][1] = __builtin_amdgcn_mfma_f32_16x16x32_bf16(af1, bfr[1][s], acc[1][1], 0, 0, 0);
      acc[2][1] = __builtin_amdgcn_mfma_f32_16x16x32_bf16(af2, bfr[1][s], acc[2][1], 0, 0, 0);
      acc[3][1] = __builtin_amdgcn_mfma_f32_16x16x32_bf16(af3, bfr[1][s], acc[3][1], 0, 0, 0);
    }

#pragma unroll
    for (int m = 0; m < 4; ++m)
#pragma unroll
      for (int t = 0; t < 2; ++t) {
        int col = cb + 16 * t + li;
        float bb = bL[col];
#pragma unroll
        for (int rp = 0; rp < 2; ++rp) {
          int rowc = 16 * m + 4 * lg + 2 * rp;
          float v0 = acc[m][t][2 * rp] + bb;
          float v1 = acc[m][t][2 * rp + 1] + bb;
          unsigned int u = pk2bf(v0, v1);
          Csm[rowc * 264 + col] = (unsigned short)(u & 0xFFFFu);
          Csm[(rowc + 1) * 264 + col] = (unsigned short)(u >> 16);
          sS[t] += v0 + v1;
          sQ[t] += v0 * v0 + v1 * v1;
        }
      }
    __syncthreads();  // B2
    for (int i = tid; i < 2048; i += 512) {
      int rowc = i >> 5, seg = i & 31;
      *(uint4*)&Y[(row0 + rowc) * 256 + seg * 8] = *(const uint4*)&Csm[rowc * 264 + seg * 8];
    }
  }

#pragma unroll
  for (int t = 0; t < 2; ++t) {
    float s = sS[t];
    s += __shfl_xor(s, 16);
    s += __shfl_xor(s, 32);
    float q = sQ[t];
    q += __shfl_xor(q, 16);
    q += __shfl_xor(q, 32);
    if (lane < 16) {
      int col = cb + 16 * t + li;
      atomicAdd(&stats[col], s);
      atomicAdd(&stats[256 + col], q);
    }
  }
}

// ---------------- MFMA GEMM stage 4 (K=256, N=64): B in regs, sorted gather, pipelined ----
__global__ __launch_bounds__(256, 4) void k_gemm4(const unsigned short* __restrict__ y3,
                                                  const float* __restrict__ ac3,
                                                  const float* __restrict__ W4, const float* __restrict__ b4,
                                                  const int* __restrict__ sorted,
                                                  unsigned short* __restrict__ h4, int P) {
  __shared__ __align__(16) char smem[34816 + 2048 + 256 + 256];
  unsigned short* A0 = (unsigned short*)smem;
  unsigned short* A1 = (unsigned short*)(smem + 17408);
  unsigned short* WTt = (unsigned short*)smem;  // transient
  float* acL = (float*)(smem + 34816);
  float* bL  = (float*)(smem + 34816 + 2048);
  int* sIdsL = (int*)(smem + 34816 + 2048 + 256);

  const int tid = threadIdx.x;
  for (int i = tid; i < 64 * 256; i += 256) {
    int k = i >> 6, n = i & 63;
    WTt[n * 264 + k] = f2bf(W4[(size_t)k * 64 + n]);
  }
  for (int i = tid; i < 512; i += 256) acL[i] = ac3[i];
  if (tid < 64) bL[tid] = b4[tid];
  __syncthreads();

  const int lane = tid & 63;
  const int w = tid >> 6;
  const int li = lane & 15, lg = lane >> 4;
  const int cb = 16 * w;
  const int tiles = P >> 6;

  short8_t bfr[8];
#pragma unroll
  for (int s = 0; s < 8; ++s)
    bfr[s] = *(const short8_t*)&WTt[(cb + li) * 264 + 32 * s + 8 * lg];
  __syncthreads();  // WTt dead

  int tb = blockIdx.x;
  if (tb >= tiles) return;
  if (tid < 64) sIdsL[tid] = sorted[tb * 64 + tid];
  __syncthreads();

  uint4 preA[4], preB[4];
#pragma unroll
  for (int it = 0; it < 4; ++it) {
    int i = tid + it * 256;
    int row = i >> 4, seg = i & 15;
    preA[it] = *(const uint4*)&y3[(size_t)sIdsL[row] * 256 + seg * 8];
  }

  for (; tb < tiles; tb += gridDim.x) {
    int nt = tb + gridDim.x;
    int sNext = 0;
    if (tid < 64 && nt < tiles) sNext = sorted[nt * 64 + tid];

#pragma unroll
    for (int it = 0; it < 4; ++it) {
      int i = tid + it * 256;
      int row = i >> 4, seg = i & 15;
      const float* ap = &acL[seg * 8];
      const float* cp = &acL[256 + seg * 8];
      uint4 o;
      o.x = aff2(preA[it].x, ap[0], cp[0], ap[1], cp[1]);
      o.y = aff2(preA[it].y, ap[2], cp[2], ap[3], cp[3]);
      o.z = aff2(preA[it].z, ap[4], cp[4], ap[5], cp[5]);
      o.w = aff2(preA[it].w, ap[6], cp[6], ap[7], cp[7]);
      *(uint4*)&A0[row * 136 + seg * 8] = o;
    }
    __syncthreads();  // B1

#pragma unroll
    for (int it = 0; it < 4; ++it) {
      int i = tid + it * 256;
      int row = i >> 4, seg = i & 15;
      preB[it] = *(const uint4*)&y3[(size_t)sIdsL[row] * 256 + 128 + seg * 8];
    }

    floatx4 acc[4];
#pragma unroll
    for (int m = 0; m < 4; ++m) acc[m] = (floatx4){0.f, 0.f, 0.f, 0.f};

#pragma unroll
    for (int s = 0; s < 4; ++s) {
      const int ko = 32 * s + 8 * lg;
      short8_t af0 = *(const short8_t*)&A0[(li) * 136 + ko];
      short8_t af1 = *(const short8_t*)&A0[(16 + li) * 136 + ko];
      short8_t af2 = *(const short8_t*)&A0[(32 + li) * 136 + ko];
      short8_t af3 = *(const short8_t*)&A0[(48 + li) * 136 + ko];
      acc[0] = __builtin_amdgcn_mfma_f32_16x16x32_bf16(af0, bfr[s], acc[0], 0, 0, 0);
      acc[1] = __builtin_amdgcn_mfma_f32_16x16x32_bf16(af1, bfr[s], acc[1], 0, 0, 0);
      acc[2] = __builtin_amdgcn_mfma_f32_16x16x32_bf16(af2, bfr[s], acc[2], 0, 0, 0);
      acc[3] = __builtin_amdgcn_mfma_f32_16x16x32_bf16(af3, bfr[s], acc[3], 0, 0, 0);
    }
    __syncthreads();  // B2

    if (tid < 64 && nt < tiles) sIdsL[tid] = sNext;
#pragma unroll
    for (int it = 0; it < 4; ++it) {
      int i = tid + it * 256;
      int row = i >> 4, seg = i & 15;
      const float* ap = &acL[128 + seg * 8];
      const float* cp = &acL[256 + 128 + seg * 8];
      uint4 o;
      o.x = aff2(preB[it].x, ap[0], cp[0], ap[1], cp[1]);
      o.y = aff2(preB[it].y, ap[2], cp[2], ap[3], cp[3]);
      o.z = aff2(preB[it].z, ap[4], cp[4], ap[5], cp[5]);
      o.w = aff2(preB[it].w, ap[6], cp[6], ap[7], cp[7]);
      *(uint4*)&A1[row * 136 + seg * 8] = o;
    }
    __syncthreads();  // B3

    if (nt < tiles) {
#pragma unroll
      for (int it = 0; it < 4; ++it) {
        int i = tid + it * 256;
        int row = i >> 4, seg = i & 15;
        preA[it] = *(const uint4*)&y3[(size_t)sIdsL[row] * 256 + seg * 8];
      }
    }

#pragma unroll
    for (int s = 0; s < 4; ++s) {
      const int ko = 32 * s + 8 * lg;
      short8_t af0 = *(const short8_t*)&A1[(li) * 136 + ko];
      short8_t af1 = *(const short8_t*)&A1[(16 + li) * 136 + ko];
      short8_t af2 = *(const short8_t*)&A1[(32 + li) * 136 + ko];
      short8_t af3 = *(const short8_t*)&A1[(48 + li) * 136 + ko];
      acc[0] = __builtin_amdgcn_mfma_f32_16x16x32_bf16(af0, bfr[4 + s], acc[0], 0, 0, 0);
      acc[1] = __builtin_amdgcn_mfma_f32_16x16x32_bf16(af1, bfr[4 + s], acc[1], 0, 0, 0);
      acc[2] = __builtin_amdgcn_mfma_f32_16x16x32_bf16(af2, bfr[4 + s], acc[2], 0, 0, 0);
      acc[3] = __builtin_amdgcn_mfma_f32_16x16x32_bf16(af3, bfr[4 + s], acc[3], 0, 0, 0);
    }
    __syncthreads();  // B4

    unsigned short* Csm = A1;  // [64][72]
    {
      int col = cb + li;
      float bb = bL[col];
#pragma unroll
      for (int m = 0; m < 4; ++m)
#pragma unroll
        for (int rp = 0; rp < 2; ++rp) {
          int rowc = 16 * m + 4 * lg + 2 * rp;
          unsigned int u = pk2bf(acc[m][2 * rp] + bb, acc[m][2 * rp + 1] + bb);
          Csm[rowc * 72 + col] = (unsigned short)(u & 0xFFFFu);
          Csm[(rowc + 1) * 72 + col] = (unsigned short)(u >> 16);
        }
    }
    __syncthreads();  // B5
    for (int i = tid; i < 512; i += 256) {
      int rowc = i >> 3, seg = i & 7;
      *(uint4*)&h4[(size_t)(tb * 64 + rowc) * 64 + seg * 8] = *(const uint4*)&Csm[rowc * 72 + seg * 8];
    }
  }
}

// ---------------- gather-mean: 8 consecutive ranks per wave (8-way MLP) ----------------
__global__ __launch_bounds__(256) void k_gather(const unsigned short* __restrict__ h4,
                                                const int2* __restrict__ rankCS,
                                                float* __restrict__ outp, int P) {
  int wv = threadIdx.x >> 6;
  int j = threadIdx.x & 63;
  int r0 = blockIdx.x * 32 + wv * 8;
  if (r0 >= P) return;
  int cnt[8], st[8];
  int maxc = 0;
#pragma unroll
  for (int i = 0; i < 8; ++i) {
    int2 cs = (r0 + i < P) ? rankCS[r0 + i] : make_int2(0, 0);
    cnt[i] = cs.x;
    st[i] = cs.y;
    maxc = max(maxc, cs.x);
  }
  float acc[8] = {};
  for (int k = 0; k < maxc; ++k) {
#pragma unroll
    for (int i = 0; i < 8; ++i)
      if (k < cnt[i]) acc[i] += bf2f(h4[(size_t)(st[i] + k) * 64 + j]);
  }
#pragma unroll
  for (int i = 0; i < 8; ++i)
    if (r0 + i < P) outp[(size_t)(r0 + i) * 64 + j] = (cnt[i] > 0) ? acc[i] / (float)cnt[i] : 0.f;
}

// ---------------- launch ----------------

extern "C" void kernel_launch(void* const* d_in, const int* in_sizes, int n_in,
                              void* d_out, int out_size, void* d_ws, size_t ws_size,
                              hipStream_t stream) {
  const float* pt_fea = (const float*)d_in[0];
  const int*   xy     = (const int*)d_in[1];
  const float* bn0_g = (const float*)d_in[2];
  const float* bn0_b = (const float*)d_in[3];
  const float* W1 = (const float*)d_in[4];
  const float* b1 = (const float*)d_in[5];
  const float* bn1_g = (const float*)d_in[6];
  const float* bn1_b = (const float*)d_in[7];
  const float* W2 = (const float*)d_in[8];
  const float* b2 = (const float*)d_in[9];
  const float* bn2_g = (const float*)d_in[10];
  const float* bn2_b = (const float*)d_in[11];
  const float* W3 = (const float*)d_in[12];
  const float* b3 = (const float*)d_in[13];
  const float* bn3_g = (const float*)d_in[14];
  const float* bn3_b = (const float*)d_in[15];
  const float* W4 = (const float*)d_in[16];
  const float* b4 = (const float*)d_in[17];

  const int P = in_sizes[0] / 9;  // 400000
  const int Nhalf = P / 2;

  char* w = (char*)d_ws;
  size_t off = 0;
  auto alloc = [&](size_t bytes) -> void* {
    off = (off + 255) & ~(size_t)255;
    void* p = w + off;
    off += bytes;
    return p;
  };
  int* counts    = (int*)alloc((size_t)NKEYS * 4);
  int* prefix    = (int*)alloc((size_t)NKEYS * 4);
  int* prefixS   = (int*)alloc((size_t)NKEYS * 4);
  int* blockTot  = (int*)alloc(512 * 4);
  int* blockOff  = (int*)alloc(512 * 4);
  int* blockTotS = (int*)alloc(512 * 4);
  int* blockOffS = (int*)alloc(512 * 4);
  int* dU        = (int*)alloc(256);
  int* flag      = (int*)alloc(256);
  int2* rankCS   = (int2*)alloc((size_t)P * 8);
  int* sorted    = (int*)alloc((size_t)P * 4);
  float* partials = (float*)alloc((size_t)2 * SQOFF * 4);
  float* st1 = (float*)alloc(512 * 4);
  float* st2 = (float*)alloc(512 * 4);
  float* st3 = (float*)alloc(512 * 4);
  float* ac0 = (float*)alloc(512 * 4);
  float* ac1 = (float*)alloc(512 * 4);
  float* ac2 = (float*)alloc(512 * 4);
  float* ac3 = (float*)alloc(512 * 4);
  unsigned short* y1 = (unsigned short*)alloc((size_t)P * 64 * 2);   // reused for h4
  unsigned short* y2 = (unsigned short*)alloc((size_t)P * 128 * 2);
  unsigned short* y3 = (unsigned short*)alloc((size_t)P * 256 * 2);
  (void)ws_size; (void)n_in; (void)out_size;
  // peak ws ~= 368 MB (r6-r21 footprint ran cleanly)

  float* out_unq = (float*)d_out;               // f32 (P,3)
  float* out_pooled = out_unq + (size_t)P * 3;  // f32 (P,64)

  const int nbP = (P + 255) / 256;

  // ---- unique + sort pipeline (fused scans / fill+pad; cursor & rankCS zeroing folded in) ----
  hipMemsetAsync(counts, 0, (size_t)NKEYS * 4, stream);
  hipMemsetAsync(st1, 0, 3 * 2048, stream);  // st1,st2,st3 contiguous
  k_detect<<<1, 1024, 0, stream>>>(xy, flag);
  k_count<<<nbP, 256, 0, stream>>>(xy, flag, counts, P, Nhalf);
  k_scan1b<<<SCAN_NB, 256, 0, stream>>>(counts, prefix, prefixS, blockTot, blockTotS);
  k_scan2b<<<2, 512, 0, stream>>>(blockTot, blockTotS, blockOff, blockOffS, dU);
  k_fillpad<<<nbP, 256, 0, stream>>>(counts, prefix, blockOff, prefixS, blockOffS, dU,
                                     out_unq, rankCS, P);
  k_sortpts<<<nbP, 256, 0, stream>>>(xy, flag, prefixS, blockOffS, counts, sorted, P, Nhalf);

  // ---- MLP ----
  k_stats9<<<STATS_NBLK, 256, 0, stream>>>(pt_fea, P, partials);
  k_finalize<<<1, 9, 0, stream>>>(partials, bn0_g, bn0_b, ac0, 9, P);

  k_stage1s<<<2048, 256, 0, stream>>>(pt_fea, ac0, W1, b1, y1, st1, P);
  k_finalize_at<<<1, 64, 0, stream>>>(st1, bn1_g, bn1_b, ac1, 64, P);

  k_gemmM<64><<<dim3(2048, 1), 256, 0, stream>>>(y1, ac1, W2, b2, y2, st2, 128, P);
  k_finalize_at<<<1, 128, 0, stream>>>(st2, bn2_g, bn2_b, ac2, 128, P);

  k_gemm3w<<<1024, 512, 0, stream>>>(y2, ac2, W3, b3, y3, st3, P);
  k_finalize_at<<<1, 256, 0, stream>>>(st3, bn3_g, bn3_b, ac3, 256, P);

  unsigned short* h4 = y1;  // y1 free after gemmM<64>
  k_gemm4<<<2048, 256, 0, stream>>>(y3, ac3, W4, b4, sorted, h4, P);

  // ---- gather mean (8 consecutive ranks per wave; slots contiguous) ----
  k_gather<<<(P + 31) / 32, 256, 0, stream>>>(h4, rankCS, out_pooled, P);
}